// Round 9
// baseline (4623.270 us; speedup 1.0000x reference)
//
#include <hip/hip_runtime.h>
#include <cstdint>
#include <cstddef>

#define NB 32
#define NT 2048
#define ND 256
#define NH 256
#define NG 1024   // 4*H
#define ROWS 16   // bt-rows per block in zx_kernel

#define TPB 512   // 8 waves = 2/EU, 1 block/CU (LDS pad forced)

typedef _Float16 h2_t __attribute__((ext_vector_type(2)));

__device__ __forceinline__ float sigf(float x) {
    return 1.0f / (1.0f + __expf(-x));
}
__device__ __forceinline__ float tanh_fast(float x) {
    return 2.0f / (1.0f + __expf(-2.0f * x)) - 1.0f;
}

__device__ __forceinline__ h2_t as_h2(uint32_t u) {
    union { uint32_t u; h2_t h; } c; c.u = u; return c.h;
}
__device__ __forceinline__ uint32_t packf16(float a, float b) {
    union { uint32_t u; h2_t h; } c;
    c.h[0] = (_Float16)a; c.h[1] = (_Float16)b;
    return c.u;
}
__device__ __forceinline__ uint16_t f16bits(float a) {
    union { uint16_t u[2]; h2_t h; } c;
    c.h[0] = (_Float16)a; c.h[1] = (_Float16)0.0f;
    return c.u[0];
}
__device__ __forceinline__ float dot2(uint32_t hpack, uint32_t wpack, float acc) {
    return __builtin_amdgcn_fdot2(as_h2(hpack), as_h2(wpack), acc, false);
}

// ---------------------------------------------------------------------------
// Phase 1: ZX[(b*NT+t)][j] = sum_k X[b,t,k] * Wi[k][j] + bias[j]
__global__ __launch_bounds__(256) void zx_kernel(const float* __restrict__ X,
                                                 const float* __restrict__ Wi,
                                                 const float* __restrict__ bias,
                                                 float* __restrict__ ZX) {
    __shared__ float xs[ROWS][ND];
    const int tid = threadIdx.x;
    const size_t row0 = (size_t)blockIdx.x * ROWS;

    const float4* Xv = (const float4*)(X + row0 * ND);
    float4* xsv = (float4*)(&xs[0][0]);
#pragma unroll
    for (int i = 0; i < (ROWS * ND / 4) / 256; ++i)
        xsv[tid + i * 256] = Xv[tid + i * 256];
    __syncthreads();

    const int j0 = tid * 4;
    const float4 bv = *(const float4*)(bias + j0);
    float acc[ROWS][4];
#pragma unroll
    for (int r = 0; r < ROWS; ++r) {
        acc[r][0] = bv.x; acc[r][1] = bv.y; acc[r][2] = bv.z; acc[r][3] = bv.w;
    }

    for (int k = 0; k < ND; ++k) {
        const float4 w = *(const float4*)(Wi + (size_t)k * NG + j0);
#pragma unroll
        for (int r = 0; r < ROWS; ++r) {
            const float x = xs[r][k];
            acc[r][0] = fmaf(x, w.x, acc[r][0]);
            acc[r][1] = fmaf(x, w.y, acc[r][1]);
            acc[r][2] = fmaf(x, w.z, acc[r][2]);
            acc[r][3] = fmaf(x, w.w, acc[r][3]);
        }
    }

#pragma unroll
    for (int r = 0; r < ROWS; ++r) {
        float4 o;
        o.x = acc[r][0]; o.y = acc[r][1]; o.z = acc[r][2]; o.w = acc[r][3];
        *(float4*)(ZX + (row0 + r) * NG + j0) = o;
    }
}

// Clears the per-pair exchange flags living in each batch's dead ZX row
// (t = 2047 is never read: lengths <= 2047 -> step index <= 2046).
__global__ void clear_flags(float* __restrict__ ZX) {
    const int i = threadIdx.x;          // 0..63 : b = i>>1, side = i&1
    if (i < 64) {
        uint32_t* exrow = (uint32_t*)(ZX + ((size_t)(i >> 1) * NT + 2047) * NG);
        exrow[512 + (i & 1)] = 0u;
    }
}

// ---------------------------------------------------------------------------
// Phase 2: pair-split persistent recurrence. 64 blocks; block (b, q) owns
// hidden units 128q..128q+127 (512 gate columns). 512 threads, 1 col/thread:
// ALL 128 weight packs register-resident (pinned) -> zero LDS weight traffic.
// Per-step h-exchange (64 u32 f16-packs + flag) via the dead ZX row t=2047,
// double-buffered by parity, agent-scope atomics. Pairing bid = q*32+b keeps
// both halves on the same XCD under round-robin dispatch (perf heuristic).
__global__
__attribute__((amdgpu_flat_work_group_size(TPB, TPB)))
__attribute__((amdgpu_waves_per_eu(2, 2)))
void rec_pair(const float* __restrict__ ZX,
              const float* __restrict__ Wh,
              const int* __restrict__ lengths,
              float* __restrict__ out)
{
    __shared__ __align__(16) unsigned char smem[96 * 1024];  // pad -> 1 block/CU
    uint32_t* hp = (uint32_t*)smem;          // 128 u32: full-h f16 packs
    float*    zs = (float*)(smem + 512);     // 512 f32 pre-activations

    const int bid = blockIdx.x;
    const int b   = bid & 31;
    const int q   = bid >> 5;
    const int tid = threadIdx.x;
    const int l   = tid & 63;
    const int w   = tid >> 6;
    const int u   = tid & 127;                       // unit-local index
    const int g   = tid >> 7;                        // gate 0..3
    const int jg  = g * 256 + q * 128 + u;           // global column

    // exchange area in the dead row of this batch
    uint32_t* exrow  = (uint32_t*)(ZX + ((size_t)b * NT + 2047) * NG);
    uint32_t* mypk   = exrow + q * 128;              // [parity*64 + slot]
    uint32_t* papk   = exrow + (1 - q) * 128;
    volatile uint32_t* myflag = exrow + 512 + q;
    volatile uint32_t* pflag  = exrow + 512 + (1 - q);

    // ---- weight staging: wp[i] = Wh pack p=(i+64q)&127 of column jg ----
    // own-half packs land at i=0..63, other-half at 64..127.
    uint32_t wp[128];
#pragma unroll
    for (int i = 0; i < 128; ++i) {
        const int p = (i + 64 * q) & 127;
        uint32_t v = packf16(Wh[(size_t)(2 * p) * NG + jg],
                             Wh[(size_t)(2 * p + 1) * NG + jg]);
        asm volatile("" : "+v"(v));                  // opaque: no remat/resink
        wp[i] = v;
    }

    if (tid < 128) hp[tid] = 0u;                     // h = 0
    float c = 0.0f, hlast = 0.0f;
    __syncthreads();

    const int len   = lengths[b];
    const int steps = (len < 1) ? 1 : len;           // output = h after step steps-1

    const uint32_t* hpo = hp + 64 * q;               // own-half packs
    const uint32_t* hpx = hp + 64 * (1 - q);         // other-half packs

    for (int t = 0; t < steps; ++t) {
        const float zx = ZX[((size_t)b * NT + t) * NG + jg];  // early issue

        float a0 = 0.0f, a1 = 0.0f;

        if (w == 0) {
            // fetch partner's h(t-1) packs -> LDS other-half
            if (t > 0) {
                while (__hip_atomic_load((const uint32_t*)pflag, __ATOMIC_ACQUIRE,
                                         __HIP_MEMORY_SCOPE_AGENT) < (uint32_t)t) {
                    __builtin_amdgcn_s_sleep(2);
                }
                const uint32_t v = __hip_atomic_load(
                    &papk[((t - 1) & 1) * 64 + l], __ATOMIC_RELAXED,
                    __HIP_MEMORY_SCOPE_AGENT);
                hp[64 * (1 - q) + l] = v;
            }
        } else {
            // own-half dots while wave 0 copies
#pragma unroll
            for (int m = 0; m < 16; ++m) {
                const uint4 h4 = *(const uint4*)(hpo + 4 * m);
                a0 = dot2(h4.x, wp[4 * m + 0], a0);
                a1 = dot2(h4.y, wp[4 * m + 1], a1);
                a0 = dot2(h4.z, wp[4 * m + 2], a0);
                a1 = dot2(h4.w, wp[4 * m + 3], a1);
            }
        }
        __syncthreads();                             // other-half hp visible

        if (w == 0) {
#pragma unroll
            for (int m = 0; m < 16; ++m) {
                const uint4 h4 = *(const uint4*)(hpo + 4 * m);
                a0 = dot2(h4.x, wp[4 * m + 0], a0);
                a1 = dot2(h4.y, wp[4 * m + 1], a1);
                a0 = dot2(h4.z, wp[4 * m + 2], a0);
                a1 = dot2(h4.w, wp[4 * m + 3], a1);
            }
        }
#pragma unroll
        for (int m = 0; m < 16; ++m) {
            const uint4 h4 = *(const uint4*)(hpx + 4 * m);
            a0 = dot2(h4.x, wp[64 + 4 * m + 0], a0);
            a1 = dot2(h4.y, wp[64 + 4 * m + 1], a1);
            a0 = dot2(h4.z, wp[64 + 4 * m + 2], a0);
            a1 = dot2(h4.w, wp[64 + 4 * m + 3], a1);
        }

        zs[tid] = zx + a0 + a1;
        __syncthreads();                             // zs complete

        // gate phase: waves 2-3 (tid 128..255), unit uu = tid-128
        if (tid >= 128 && tid < 256) {
            const int uu = tid - 128;
            const float iv = zs[uu];
            const float fv = zs[128 + uu];
            const float gv = zs[256 + uu];
            const float ov = zs[384 + uu];
            c = sigf(fv) * c + sigf(iv) * tanh_fast(gv);
            hlast = sigf(ov) * tanh_fast(c);
            const uint32_t hb = (uint32_t)f16bits(hlast);
            const uint32_t nb = __shfl_xor(hb, 1);
            if ((uu & 1) == 0) {
                const uint32_t pk = hb | (nb << 16);
                hp[64 * q + (uu >> 1)] = pk;         // own-half for next step
                __hip_atomic_store(&mypk[(t & 1) * 64 + (uu >> 1)], pk,
                                   __ATOMIC_RELAXED, __HIP_MEMORY_SCOPE_AGENT);
            }
        }
        __syncthreads();                             // hp + pack stores done
        if (tid == 0) {
            __hip_atomic_store((uint32_t*)myflag, (uint32_t)(t + 1),
                               __ATOMIC_RELEASE, __HIP_MEMORY_SCOPE_AGENT);
        }
    }

    if (tid >= 128 && tid < 256)
        out[(size_t)b * NH + 128 * q + (tid - 128)] = hlast;
}

// ---------------------------------------------------------------------------
// Fallback recurrence (streams weights; used only if ws can't hold ZX)
__global__ __launch_bounds__(512) void rec_fallback(
    const float* __restrict__ X,
    const float* __restrict__ Wi,
    const float* __restrict__ Wh,
    const float* __restrict__ bias,
    const int* __restrict__ lengths,
    float* __restrict__ out)
{
    __shared__ float hs[NH];
    __shared__ float zs[NG];
    __shared__ float xs[ND];

    const int b   = blockIdx.x;
    const int tid = threadIdx.x;
    const int c0  = tid * 2;

    const int len   = lengths[b];
    const int steps = (len < 1) ? 1 : len;

    float c_state = 0.0f;
    if (tid < NH) hs[tid] = 0.0f;
    const float b0 = bias[c0], b1 = bias[c0 + 1];
    __syncthreads();

    for (int t = 0; t < steps; ++t) {
        float a0 = b0, a1 = b1;
        if (tid < ND) xs[tid] = X[((size_t)b * NT + t) * ND + tid];
        __syncthreads();
#pragma unroll 2
        for (int k = 0; k < ND; k += 4) {
            const float4 xv = *(const float4*)(xs + k);
            const float2 w0 = *(const float2*)(Wi + (size_t)(k + 0) * NG + c0);
            const float2 w1 = *(const float2*)(Wi + (size_t)(k + 1) * NG + c0);
            const float2 w2 = *(const float2*)(Wi + (size_t)(k + 2) * NG + c0);
            const float2 w3 = *(const float2*)(Wi + (size_t)(k + 3) * NG + c0);
            a0 = fmaf(xv.x, w0.x, a0); a1 = fmaf(xv.x, w0.y, a1);
            a0 = fmaf(xv.y, w1.x, a0); a1 = fmaf(xv.y, w1.y, a1);
            a0 = fmaf(xv.z, w2.x, a0); a1 = fmaf(xv.z, w2.y, a1);
            a0 = fmaf(xv.w, w3.x, a0); a1 = fmaf(xv.w, w3.y, a1);
        }
#pragma unroll 2
        for (int k = 0; k < NH; k += 4) {
            const float4 hv = *(const float4*)(hs + k);
            const float2 w0 = *(const float2*)(Wh + (size_t)(k + 0) * NG + c0);
            const float2 w1 = *(const float2*)(Wh + (size_t)(k + 1) * NG + c0);
            const float2 w2 = *(const float2*)(Wh + (size_t)(k + 2) * NG + c0);
            const float2 w3 = *(const float2*)(Wh + (size_t)(k + 3) * NG + c0);
            a0 = fmaf(hv.x, w0.x, a0); a1 = fmaf(hv.x, w0.y, a1);
            a0 = fmaf(hv.y, w1.x, a0); a1 = fmaf(hv.y, w1.y, a1);
            a0 = fmaf(hv.z, w2.x, a0); a1 = fmaf(hv.z, w2.y, a1);
            a0 = fmaf(hv.w, w3.x, a0); a1 = fmaf(hv.w, w3.y, a1);
        }

        float2 zo2; zo2.x = a0; zo2.y = a1;
        *(float2*)(zs + c0) = zo2;
        __syncthreads();

        if (tid < NH) {
            const float iv = zs[tid];
            const float fv = zs[NH + tid];
            const float gv = zs[2 * NH + tid];
            const float ov = zs[3 * NH + tid];
            c_state = sigf(fv) * c_state + sigf(iv) * tanh_fast(gv);
            hs[tid] = sigf(ov) * tanh_fast(c_state);
        }
        __syncthreads();
    }

    if (tid < NH) out[(size_t)b * NH + tid] = hs[tid];
}

extern "C" void kernel_launch(void* const* d_in, const int* in_sizes, int n_in,
                              void* d_out, int out_size, void* d_ws, size_t ws_size,
                              hipStream_t stream) {
    const float* X       = (const float*)d_in[0];
    const int*   lengths = (const int*)d_in[1];
    const float* Wi      = (const float*)d_in[2];
    const float* Wh      = (const float*)d_in[3];
    const float* bias    = (const float*)d_in[4];
    float* out = (float*)d_out;

    const size_t zx_bytes = (size_t)NB * NT * NG * sizeof(float);  // 256 MB
    float* ZX = (float*)d_ws;

    if (ws_size >= zx_bytes) {
        zx_kernel<<<dim3((NB * NT) / ROWS), dim3(256), 0, stream>>>(X, Wi, bias, ZX);
        clear_flags<<<dim3(1), dim3(64), 0, stream>>>(ZX);
        rec_pair<<<dim3(64), dim3(TPB), 0, stream>>>(ZX, Wh, lengths, out);
    } else {
        rec_fallback<<<dim3(NB), dim3(512), 0, stream>>>(X, Wi, Wh, bias, lengths, out);
    }
}